// Round 14
// baseline (58.720 us; speedup 1.0000x reference)
//
#include <hip/hip_runtime.h>
#include <hip/hip_bf16.h>

#define HW 128
#define PW 130   // padded width/height

typedef float f32x4 __attribute__((ext_vector_type(4)));
typedef short bf16x8 __attribute__((ext_vector_type(8)));

__device__ __forceinline__ unsigned short f2bf(float v) {
  __hip_bfloat16 h = __float2bfloat16(v);
  return *reinterpret_cast<unsigned short*>(&h);
}

__device__ __forceinline__ void bf8_to_f32(const int4& r, float* f) {
  const unsigned int* u = reinterpret_cast<const unsigned int*>(&r);
#pragma unroll
  for (int k = 0; k < 4; ++k) {
    f[2 * k]     = __uint_as_float(u[k] << 16);
    f[2 * k + 1] = __uint_as_float(u[k] & 0xffff0000u);
  }
}

__device__ __forceinline__ void gld_lds16(const void* g, void* l) {
  __builtin_amdgcn_global_load_lds(
      (const __attribute__((address_space(1))) void*)g,
      (__attribute__((address_space(3))) void*)l, 16, 0, 0);
}

// ---------------- k_tr: prep + border-zero + NCHW->padded-NHWC transpose ----------------
// wfrag: main-GEMM B in MFMA fragment order (r10/r11-verified):
//   frag f = t*8 + ot*2 + kk; elem i = f*512 + lane*8 + j
//   wfrag[i] = bf16(w[o=ot*16+(lane&15)][c=(kk*4+(lane>>4))*8+j][t])
// wb: offsets-conv B frags (r8-verified layout).
__global__ __launch_bounds__(256) void k_tr(const float* __restrict__ x,
                                            unsigned int* __restrict__ xt_u32,
                                            const float* __restrict__ w,
                                            const float* __restrict__ w_off,
                                            unsigned short* __restrict__ wfrag,
                                            unsigned short* __restrict__ wb) {
  __shared__ float tile[64 * 129];
  int blk = blockIdx.x;                   // b*128 + h
  int tid = threadIdx.x;
  int gi = blk * 256 + tid;

  // ---- folded prep ----
  if (blk < 144) {
    if (gi < 36864) {                     // 72 frags * 512
      int j = gi & 7, lane = (gi >> 3) & 63, f = gi >> 9;
      int kk = f & 1, ot = (f >> 1) & 3, t = f >> 3;
      int o = ot * 16 + (lane & 15);
      int c = (kk * 4 + (lane >> 4)) * 8 + j;
      wfrag[gi] = f2bf(w[o * 576 + c * 9 + t]);
    }
    if (gi < 18432) {
      int j = gi & 7, lane = (gi >> 3) & 63, f = gi >> 9;
      int n = f & 1, kk = (f >> 1) & 1, t = f >> 2;
      int o = n * 16 + (lane & 15);
      int c = kk * 32 + (lane >> 4) * 8 + j;
      float v = (o < 18) ? w_off[o * 576 + c * 9 + t] : 0.0f;
      wb[gi] = f2bf(v);
    }
  }
  // ---- folded border zero: 2064 cells * 8 int4 ----
  if (gi < 16512) {
    int c4 = gi & 7, ci = gi >> 3;
    int b = ci / 516, cell = ci - b * 516;
    int row, col;
    if (cell < 130)      { row = 0;   col = cell; }
    else if (cell < 260) { row = 129; col = cell - 130; }
    else { int k = cell - 260; row = 1 + (k >> 1); col = (k & 1) ? 129 : 0; }
    reinterpret_cast<int4*>(xt_u32 + ((size_t)(b * PW + row) * PW + col) * 32)[c4] =
        make_int4(0, 0, 0, 0);
  }

  // ---- transpose (r8-verified) ----
  int h = blk & 127, b = blk >> 7;
  int w0 = tid & 127, ch = tid >> 7;
  const float* xb = x + ((size_t)b * 64 * HW + h) * HW;
#pragma unroll
  for (int k = 0; k < 32; ++k) {
    int c = ch * 32 + k;
    tile[c * 129 + (w0 ^ (c & 1))] = xb[c * (HW * HW) + w0];
  }
  __syncthreads();
  int c2 = tid & 31, wg = tid >> 5;
#pragma unroll
  for (int k = 0; k < 16; ++k) {
    int ww = wg * 16 + k;
    float lo = tile[(2 * c2) * 129 + ww];
    float hi = tile[(2 * c2 + 1) * 129 + (ww ^ 1)];
    xt_u32[((size_t)(b * PW + h + 1) * PW + (ww + 1)) * 32 + c2] =
        (unsigned int)f2bf(lo) | ((unsigned int)f2bf(hi) << 16);
  }
}

// ---------------- k_fuse: phase-0 conv + barrier-free reg-A/reg-B main loop ----------------
// Wave w owns M=16 pixels x N=64 outputs; thread (l15=pixel, l4=chunk).
// Main loop: NO LDS, NO barriers — per tap: load Bc (8 int4, L1-hot), issue
// gather(t+1) (8 int4, L2), MFMA(t) [waits vmcnt(8), gathers stay in flight],
// lerp(t+1). Waves run independently -> latency hidden by TLP; setprio on MFMA.
// LDS 29952: phase-0 slab [0,25344) + loff [25344,29952).
__global__ __launch_bounds__(256) void k_fuse(const unsigned short* __restrict__ xt,
                                              const unsigned short* __restrict__ wb,
                                              const unsigned short* __restrict__ wfrag,
                                              const float* __restrict__ b_off,
                                              const float* __restrict__ bias,
                                              float* __restrict__ out) {
  __shared__ __align__(16) char u_lds[29952];
  char* slab_b = u_lds;
  unsigned short* slab_us = (unsigned short*)u_lds;
  float* loff = (float*)(u_lds + 25344);

  int bid = blockIdx.x;
  bid = (bid & 7) * 128 + (bid >> 3);     // XCD swizzle (1024 % 8 == 0)
  int pix0 = bid * 64;
  int h = (pix0 >> 7) & 127, b = pix0 >> 14, wbase = pix0 & 127;

  int tid = threadIdx.x;
  int wid = tid >> 6, lane = tid & 63;
  int l15 = lane & 15, l4 = lane >> 4;

  const unsigned short* xb = xt + (size_t)b * (PW * PW * 64);

  // ======== phase 0: offsets conv (r8/r11-verified) ========
  for (int i = wid; i < 25; i += 4) {
    int e = i * 512 + lane * 8;
    if (e < 12672) {
      int S = e >> 6, c8 = (e >> 3) & 7;
      int r = S / 66, u = S - r * 66;
      gld_lds16(xb + ((size_t)((h + r) * PW + wbase + u)) * 64 + ((c8 ^ (S & 7)) << 3),
                &slab_us[i * 512]);
    }
  }

  const int4* wb4 = reinterpret_cast<const int4*>(wb);
  int4 bc[4], bn[4];
#pragma unroll
  for (int q = 0; q < 4; ++q) bc[q] = wb4[q * 64 + lane];
  asm volatile("s_waitcnt vmcnt(0)" ::: "memory");
  __builtin_amdgcn_s_barrier();

  f32x4 acc0 = {0.f, 0.f, 0.f, 0.f}, acc1 = {0.f, 0.f, 0.f, 0.f};
#pragma unroll 1
  for (int t = 0; t < 9; ++t) {
    if (t < 8) {
#pragma unroll
      for (int q = 0; q < 4; ++q) bn[q] = wb4[((t + 1) * 4 + q) * 64 + lane];
    }
    int ti = t / 3, tj = t - ti * 3;
    int S = ti * 66 + (wid * 16 + l15) + tj;
#pragma unroll
    for (int kk = 0; kk < 2; ++kk) {
      int phys = (kk * 4 + l4) ^ (S & 7);
      bf16x8 a = *reinterpret_cast<const bf16x8*>(slab_b + S * 128 + phys * 16);
      acc0 = __builtin_amdgcn_mfma_f32_16x16x32_bf16(a, *(const bf16x8*)&bc[kk * 2 + 0], acc0, 0, 0, 0);
      acc1 = __builtin_amdgcn_mfma_f32_16x16x32_bf16(a, *(const bf16x8*)&bc[kk * 2 + 1], acc1, 0, 0, 0);
    }
#pragma unroll
    for (int q = 0; q < 4; ++q) bc[q] = bn[q];
  }
  {
    float bo0 = b_off[l15];
    int pl = wid * 16 + l4 * 4;
#pragma unroll
    for (int reg = 0; reg < 4; ++reg)
      loff[(pl + reg) * 18 + l15] = acc0[reg] + bo0;
    if (l15 < 2) {
      float bo1 = b_off[16 + l15];
#pragma unroll
      for (int reg = 0; reg < 4; ++reg)
        loff[(pl + reg) * 18 + 16 + l15] = acc1[reg] + bo1;
    }
  }
  __syncthreads();   // loff visible to all lanes (last barrier in the kernel)

  // ======== main loop: barrier-free ========
  int p = wid * 16 + l15;                 // this thread's pixel (0..63)
  int pxx = wbase + p;
  const float* lp = loff + p * 18;
  const unsigned short* xch = xb + l4 * 8;

  int4 rc[8];
  float fw0, fw1, fw2, fw3;

  auto gather = [&](int t) {
    int ti = t / 3, tj = t % 3;
    float2 d = *reinterpret_cast<const float2*>(lp + 2 * t);
    float py = (float)(h + ti - 1) + d.x;
    float px = (float)(pxx + tj - 1) + d.y;
    float y0f = floorf(py), x0f = floorf(px);
    float wy = py - y0f, wxf = px - x0f;
    int y0 = (int)y0f, x0 = (int)x0f;
    int y1 = y0 + 1, x1 = x0 + 1;
    fw0 = (((unsigned)y0 < HW) && ((unsigned)x0 < HW)) ? (1.f - wy) * (1.f - wxf) : 0.f;
    fw1 = (((unsigned)y0 < HW) && ((unsigned)x1 < HW)) ? (1.f - wy) * wxf : 0.f;
    fw2 = (((unsigned)y1 < HW) && ((unsigned)x0 < HW)) ? wy * (1.f - wxf) : 0.f;
    fw3 = (((unsigned)y1 < HW) && ((unsigned)x1 < HW)) ? wy * wxf : 0.f;
    int y0c = min(max(y0, 0), HW - 1) + 1, y1c = min(max(y1, 0), HW - 1) + 1;
    int x0c = min(max(x0, 0), HW - 1) + 1, x1c = min(max(x1, 0), HW - 1) + 1;
    const unsigned short* b00 = xch + ((size_t)y0c * PW + x0c) * 64;
    const unsigned short* b01 = xch + ((size_t)y0c * PW + x1c) * 64;
    const unsigned short* b10 = xch + ((size_t)y1c * PW + x0c) * 64;
    const unsigned short* b11 = xch + ((size_t)y1c * PW + x1c) * 64;
    rc[0] = *reinterpret_cast<const int4*>(b00);
    rc[1] = *reinterpret_cast<const int4*>(b00 + 32);
    rc[2] = *reinterpret_cast<const int4*>(b01);
    rc[3] = *reinterpret_cast<const int4*>(b01 + 32);
    rc[4] = *reinterpret_cast<const int4*>(b10);
    rc[5] = *reinterpret_cast<const int4*>(b10 + 32);
    rc[6] = *reinterpret_cast<const int4*>(b11);
    rc[7] = *reinterpret_cast<const int4*>(b11 + 32);
  };

  int4 af[2];
  auto lerp = [&]() {
#pragma unroll
    for (int j = 0; j < 2; ++j) {
      float v00[8], v01[8], v10[8], v11[8];
      bf8_to_f32(rc[0 + j], v00); bf8_to_f32(rc[2 + j], v01);
      bf8_to_f32(rc[4 + j], v10); bf8_to_f32(rc[6 + j], v11);
      unsigned int pk[4];
#pragma unroll
      for (int jj = 0; jj < 4; ++jj) {
        float slo = fmaf(v11[2 * jj], fw3,
                    fmaf(v10[2 * jj], fw2,
                    fmaf(v01[2 * jj], fw1, v00[2 * jj] * fw0)));
        float shi = fmaf(v11[2 * jj + 1], fw3,
                    fmaf(v10[2 * jj + 1], fw2,
                    fmaf(v01[2 * jj + 1], fw1, v00[2 * jj + 1] * fw0)));
        pk[jj] = (unsigned int)f2bf(slo) | ((unsigned int)f2bf(shi) << 16);
      }
      af[j] = *reinterpret_cast<int4*>(pk);
    }
  };

  const int4* wf4 = reinterpret_cast<const int4*>(wfrag);
  int4 Bc[8];

  f32x4 acc[4];
#pragma unroll
  for (int fn = 0; fn < 4; ++fn) acc[fn] = {0.f, 0.f, 0.f, 0.f};

  gather(0);
  lerp();

#pragma unroll 1
  for (int t = 0; t < 9; ++t) {
    // B frags first (so MFMA's wait leaves the gather loads in flight)
#pragma unroll
    for (int q = 0; q < 8; ++q) Bc[q] = wf4[(t * 8 + q) * 64 + lane];
    if (t < 8) gather(t + 1);             // L2 loads, in flight across MFMA+lerp

    __builtin_amdgcn_s_setprio(1);
#pragma unroll
    for (int kk = 0; kk < 2; ++kk) {
#pragma unroll
      for (int fn = 0; fn < 4; ++fn) {
        acc[fn] = __builtin_amdgcn_mfma_f32_16x16x32_bf16(
            *reinterpret_cast<const bf16x8*>(&af[kk]),
            *reinterpret_cast<const bf16x8*>(&Bc[fn * 2 + kk]),
            acc[fn], 0, 0, 0);
      }
    }
    __builtin_amdgcn_s_setprio(0);
    if (t < 8) lerp();                    // waits rc vmcnt; builds af for t+1
  }

  // epilogue: D col=l15 -> o (within fn-tile), row=l4*4+reg -> pixel (r13-verified)
  int hwbase = (pix0 & 16383) + wid * 16 + l4 * 4;
  int bb = pix0 >> 14;
#pragma unroll
  for (int fn = 0; fn < 4; ++fn) {
    int o = fn * 16 + l15;
    float bz = bias[o];
    float4 st = make_float4(acc[fn][0] + bz, acc[fn][1] + bz,
                            acc[fn][2] + bz, acc[fn][3] + bz);
    *reinterpret_cast<float4*>(&out[(((size_t)bb * 64 + o) << 14) + hwbase]) = st;
  }
}

extern "C" void kernel_launch(void* const* d_in, const int* in_sizes, int n_in,
                              void* d_out, int out_size, void* d_ws, size_t ws_size,
                              hipStream_t stream) {
  const float* x     = (const float*)d_in[0];
  const float* w_off = (const float*)d_in[1];
  const float* b_off = (const float*)d_in[2];
  const float* w     = (const float*)d_in[3];
  const float* bias  = (const float*)d_in[4];
  float* out = (float*)d_out;
  char* ws   = (char*)d_ws;

  // ws layout (BYTES):
  //   wfrag [0,       73,728)      36,864 bf16 (main-GEMM B, frag-ordered)
  //   wb    [73,728,  110,592)     18,432 bf16 (offsets-conv B frags)
  //   xt    [110,592, 8,763,392)   4*130*130*64 bf16 (padded, zero border)
  unsigned short* wfrag = (unsigned short*)(ws);
  unsigned short* wb    = (unsigned short*)(ws + 73728);
  unsigned short* xt    = (unsigned short*)(ws + 110592);

  hipLaunchKernelGGL(k_tr,   dim3(512),  dim3(256), 0, stream,
                     x, (unsigned int*)xt, w, w_off, wfrag, wb);
  hipLaunchKernelGGL(k_fuse, dim3(1024), dim3(256), 0, stream,
                     xt, wb, wfrag, b_off, bias, out);
}

// Round 15
// 47.504 us; speedup vs baseline: 1.2361x; 1.2361x over previous
//
#include <hip/hip_runtime.h>
#include <hip/hip_bf16.h>

#define HW 128
#define PW 130   // padded width/height

typedef float f32x4 __attribute__((ext_vector_type(4)));
typedef short bf16x8 __attribute__((ext_vector_type(8)));

__device__ __forceinline__ unsigned short f2bf(float v) {
  __hip_bfloat16 h = __float2bfloat16(v);
  return *reinterpret_cast<unsigned short*>(&h);
}

__device__ __forceinline__ void bf8_to_f32(const int4& r, float* f) {
  const unsigned int* u = reinterpret_cast<const unsigned int*>(&r);
#pragma unroll
  for (int k = 0; k < 4; ++k) {
    f[2 * k]     = __uint_as_float(u[k] << 16);
    f[2 * k + 1] = __uint_as_float(u[k] & 0xffff0000u);
  }
}

__device__ __forceinline__ void gld_lds16(const void* g, void* l) {
  __builtin_amdgcn_global_load_lds(
      (const __attribute__((address_space(1))) void*)g,
      (__attribute__((address_space(3))) void*)l, 16, 0, 0);
}

// ---------------- k_tr: prep + border-zero + NCHW->padded-NHWC transpose (r14-verified) ----
// wfrag: frag f = t*8 + ot*2 + kk; elem i = f*512 + lane*8 + j
//   wfrag[i] = bf16(w[o=ot*16+(lane&15)][c=(kk*4+(lane>>4))*8+j][t])
// wb: offsets-conv B frags (r8-verified layout).
__global__ __launch_bounds__(256) void k_tr(const float* __restrict__ x,
                                            unsigned int* __restrict__ xt_u32,
                                            const float* __restrict__ w,
                                            const float* __restrict__ w_off,
                                            unsigned short* __restrict__ wfrag,
                                            unsigned short* __restrict__ wb) {
  __shared__ float tile[64 * 129];
  int blk = blockIdx.x;                   // b*128 + h
  int tid = threadIdx.x;
  int gi = blk * 256 + tid;

  if (blk < 144) {
    if (gi < 36864) {
      int j = gi & 7, lane = (gi >> 3) & 63, f = gi >> 9;
      int kk = f & 1, ot = (f >> 1) & 3, t = f >> 3;
      int o = ot * 16 + (lane & 15);
      int c = (kk * 4 + (lane >> 4)) * 8 + j;
      wfrag[gi] = f2bf(w[o * 576 + c * 9 + t]);
    }
    if (gi < 18432) {
      int j = gi & 7, lane = (gi >> 3) & 63, f = gi >> 9;
      int n = f & 1, kk = (f >> 1) & 1, t = f >> 2;
      int o = n * 16 + (lane & 15);
      int c = kk * 32 + (lane >> 4) * 8 + j;
      float v = (o < 18) ? w_off[o * 576 + c * 9 + t] : 0.0f;
      wb[gi] = f2bf(v);
    }
  }
  if (gi < 16512) {
    int c4 = gi & 7, ci = gi >> 3;
    int b = ci / 516, cell = ci - b * 516;
    int row, col;
    if (cell < 130)      { row = 0;   col = cell; }
    else if (cell < 260) { row = 129; col = cell - 130; }
    else { int k = cell - 260; row = 1 + (k >> 1); col = (k & 1) ? 129 : 0; }
    reinterpret_cast<int4*>(xt_u32 + ((size_t)(b * PW + row) * PW + col) * 32)[c4] =
        make_int4(0, 0, 0, 0);
  }

  int h = blk & 127, b = blk >> 7;
  int w0 = tid & 127, ch = tid >> 7;
  const float* xb = x + ((size_t)b * 64 * HW + h) * HW;
#pragma unroll
  for (int k = 0; k < 32; ++k) {
    int c = ch * 32 + k;
    tile[c * 129 + (w0 ^ (c & 1))] = xb[c * (HW * HW) + w0];
  }
  __syncthreads();
  int c2 = tid & 31, wg = tid >> 5;
#pragma unroll
  for (int k = 0; k < 16; ++k) {
    int ww = wg * 16 + k;
    float lo = tile[(2 * c2) * 129 + ww];
    float hi = tile[(2 * c2 + 1) * 129 + (ww ^ 1)];
    xt_u32[((size_t)(b * PW + h + 1) * PW + (ww + 1)) * 32 + c2] =
        (unsigned int)f2bf(lo) | ((unsigned int)f2bf(hi) << 16);
  }
}

// ---------------- k_fuse: 8-wave K-split — phase-0 conv + LDS-A gather + MFMA ----------------
// Wave w8: pg = w8>>1 (16 pixels), kh = w8&1 (K-half: channels kh*32..+31).
// 8192 total waves -> 32/CU (vs 4096/16 before): the TLP the r9-r14 plateau lacked.
// LDS 29952: slab [0,25344) (union: ldsA dbuf 2x8192, epilogue scratch 16K); loff @25344.
__global__ __launch_bounds__(512) void k_fuse(const unsigned short* __restrict__ xt,
                                              const unsigned short* __restrict__ wb,
                                              const unsigned short* __restrict__ wfrag,
                                              const float* __restrict__ b_off,
                                              const float* __restrict__ bias,
                                              float* __restrict__ out) {
  __shared__ __align__(16) char u_lds[29952];
  char* slab_b = u_lds;
  unsigned short* slab_us = (unsigned short*)u_lds;
  float* loff = (float*)(u_lds + 25344);

  int bid = blockIdx.x;
  bid = (bid & 7) * 128 + (bid >> 3);     // XCD swizzle (1024 % 8 == 0)
  int pix0 = bid * 64;
  int h = (pix0 >> 7) & 127, b = pix0 >> 14, wbase = pix0 & 127;

  int tid = threadIdx.x;
  int w8 = tid >> 6, lane = tid & 63;
  int pg = w8 >> 1, kh = w8 & 1;
  int l15 = lane & 15, l4 = lane >> 4;

  const unsigned short* xb = xt + (size_t)b * (PW * PW * 64);

  // ======== phase 0: offsets conv, K-split ========
  for (int i = w8; i < 25; i += 8) {
    int e = i * 512 + lane * 8;
    if (e < 12672) {
      int S = e >> 6, c8 = (e >> 3) & 7;
      int r = S / 66, u = S - r * 66;
      gld_lds16(xb + ((size_t)((h + r) * PW + wbase + u)) * 64 + ((c8 ^ (S & 7)) << 3),
                &slab_us[i * 512]);
    }
  }

  const int4* wb4 = reinterpret_cast<const int4*>(wb);
  int4 bc[2], bn[2];
#pragma unroll
  for (int n = 0; n < 2; ++n) bc[n] = wb4[(kh * 2 + n) * 64 + lane];
  asm volatile("s_waitcnt vmcnt(0)" ::: "memory");
  __builtin_amdgcn_s_barrier();

  f32x4 acc0 = {0.f, 0.f, 0.f, 0.f}, acc1 = {0.f, 0.f, 0.f, 0.f};
#pragma unroll 1
  for (int t = 0; t < 9; ++t) {
    if (t < 8) {
#pragma unroll
      for (int n = 0; n < 2; ++n) bn[n] = wb4[((t + 1) * 4 + kh * 2 + n) * 64 + lane];
    }
    int ti = t / 3, tj = t - ti * 3;
    int S = ti * 66 + (pg * 16 + l15) + tj;
    int phys = (kh * 4 + l4) ^ (S & 7);
    bf16x8 a = *reinterpret_cast<const bf16x8*>(slab_b + S * 128 + phys * 16);
    acc0 = __builtin_amdgcn_mfma_f32_16x16x32_bf16(a, *(const bf16x8*)&bc[0], acc0, 0, 0, 0);
    acc1 = __builtin_amdgcn_mfma_f32_16x16x32_bf16(a, *(const bf16x8*)&bc[1], acc1, 0, 0, 0);
#pragma unroll
    for (int n = 0; n < 2; ++n) bc[n] = bn[n];
  }
  // combine the two K-halves into loff: kh=0 writes (+bias), barrier, kh=1 adds
  {
    int pl = pg * 16 + l4 * 4;
    if (kh == 0) {
      float bo0 = b_off[l15];
#pragma unroll
      for (int reg = 0; reg < 4; ++reg)
        loff[(pl + reg) * 18 + l15] = acc0[reg] + bo0;
      if (l15 < 2) {
        float bo1 = b_off[16 + l15];
#pragma unroll
        for (int reg = 0; reg < 4; ++reg)
          loff[(pl + reg) * 18 + 16 + l15] = acc1[reg] + bo1;
      }
    }
    __syncthreads();
    if (kh == 1) {
#pragma unroll
      for (int reg = 0; reg < 4; ++reg)
        loff[(pl + reg) * 18 + l15] += acc0[reg];
      if (l15 < 2) {
#pragma unroll
        for (int reg = 0; reg < 4; ++reg)
          loff[(pl + reg) * 18 + 16 + l15] += acc1[reg];
      }
    }
    __syncthreads();   // loff final; slab dead -> ldsA union safe
  }

  // ======== main loop ========
  auto ldsAp = [&](int s) { return (unsigned short*)(u_lds + s * 8192); };

  int g = tid & 7, gp = tid >> 3;         // gather: chunk g, pixel gp (0..63)
  int pxx = wbase + gp;
  const float* lp = loff + gp * 18;
  const unsigned short* xch = xb + g * 8;

  int4 rc[4];
  float fw0, fw1, fw2, fw3;

  auto gather = [&](int t) {
    int ti = t / 3, tj = t % 3;
    float2 d = *reinterpret_cast<const float2*>(lp + 2 * t);
    float py = (float)(h + ti - 1) + d.x;
    float px = (float)(pxx + tj - 1) + d.y;
    float y0f = floorf(py), x0f = floorf(px);
    float wy = py - y0f, wxf = px - x0f;
    int y0 = (int)y0f, x0 = (int)x0f;
    int y1 = y0 + 1, x1 = x0 + 1;
    fw0 = (((unsigned)y0 < HW) && ((unsigned)x0 < HW)) ? (1.f - wy) * (1.f - wxf) : 0.f;
    fw1 = (((unsigned)y0 < HW) && ((unsigned)x1 < HW)) ? (1.f - wy) * wxf : 0.f;
    fw2 = (((unsigned)y1 < HW) && ((unsigned)x0 < HW)) ? wy * (1.f - wxf) : 0.f;
    fw3 = (((unsigned)y1 < HW) && ((unsigned)x1 < HW)) ? wy * wxf : 0.f;
    int y0c = min(max(y0, 0), HW - 1) + 1, y1c = min(max(y1, 0), HW - 1) + 1;
    int x0c = min(max(x0, 0), HW - 1) + 1, x1c = min(max(x1, 0), HW - 1) + 1;
    rc[0] = *reinterpret_cast<const int4*>(xch + ((size_t)y0c * PW + x0c) * 64);
    rc[1] = *reinterpret_cast<const int4*>(xch + ((size_t)y0c * PW + x1c) * 64);
    rc[2] = *reinterpret_cast<const int4*>(xch + ((size_t)y1c * PW + x0c) * 64);
    rc[3] = *reinterpret_cast<const int4*>(xch + ((size_t)y1c * PW + x1c) * 64);
  };

  auto lerp_write = [&](int bsel) {
    float v00[8], v01[8], v10[8], v11[8];
    bf8_to_f32(rc[0], v00); bf8_to_f32(rc[1], v01);
    bf8_to_f32(rc[2], v10); bf8_to_f32(rc[3], v11);
    unsigned int pk[4];
#pragma unroll
    for (int jj = 0; jj < 4; ++jj) {
      float slo = fmaf(v11[2 * jj], fw3,
                  fmaf(v10[2 * jj], fw2,
                  fmaf(v01[2 * jj], fw1, v00[2 * jj] * fw0)));
      float shi = fmaf(v11[2 * jj + 1], fw3,
                  fmaf(v10[2 * jj + 1], fw2,
                  fmaf(v01[2 * jj + 1], fw1, v00[2 * jj + 1] * fw0)));
      pk[jj] = (unsigned int)f2bf(slo) | ((unsigned int)f2bf(shi) << 16);
    }
    *reinterpret_cast<int4*>(&ldsAp(bsel)[gp * 64 + ((g ^ (gp & 7)) << 3)]) =
        *reinterpret_cast<int4*>(pk);
  };

  const int4* wf4 = reinterpret_cast<const int4*>(wfrag);
  int4 Bc[4], Bn[4];
#pragma unroll
  for (int ot = 0; ot < 4; ++ot) Bc[ot] = wf4[(ot * 2 + kh) * 64 + lane];

  f32x4 acc[4];
#pragma unroll
  for (int ot = 0; ot < 4; ++ot) acc[ot] = {0.f, 0.f, 0.f, 0.f};

  // prologue: A0 built in LDS
  gather(0);
  lerp_write(0);
  __syncthreads();

  int prow = pg * 16 + l15;
  int aoff = prow * 128 + (((kh * 4 + l4) ^ (prow & 7)) << 4);

#pragma unroll 1
  for (int t = 0; t < 9; ++t) {
    int cur = t & 1;
    if (t < 8) {
#pragma unroll
      for (int ot = 0; ot < 4; ++ot)
        Bn[ot] = wf4[((t + 1) * 8 + ot * 2 + kh) * 64 + lane];
      gather(t + 1);                      // L2 loads in flight under MFMA
    }
    bf16x8 a = *reinterpret_cast<const bf16x8*>((char*)ldsAp(cur) + aoff);
    __builtin_amdgcn_s_setprio(1);
#pragma unroll
    for (int ot = 0; ot < 4; ++ot)
      acc[ot] = __builtin_amdgcn_mfma_f32_16x16x32_bf16(
          a, *(const bf16x8*)&Bc[ot], acc[ot], 0, 0, 0);
    __builtin_amdgcn_s_setprio(0);
    if (t < 8) lerp_write(cur ^ 1);       // waits rc vmcnt; writes other buffer
#pragma unroll
    for (int ot = 0; ot < 4; ++ot) Bc[ot] = Bn[ot];
    __syncthreads();
  }

  // ======== epilogue: reduce K-halves via LDS (unions dead ldsA) ========
  f32x4* scr = (f32x4*)u_lds;             // 256*4*16B = 16KB
  int sidx = (pg * 64 + lane) * 4;
  if (kh == 1) {
#pragma unroll
    for (int ot = 0; ot < 4; ++ot) scr[sidx + ot] = acc[ot];
  }
  __syncthreads();
  if (kh == 0) {
    int hwbase = (pix0 & 16383) + pg * 16 + l4 * 4;
    int bb = pix0 >> 14;
#pragma unroll
    for (int ot = 0; ot < 4; ++ot) {
      f32x4 s = scr[sidx + ot];
      int o = ot * 16 + l15;
      float bz = bias[o];
      float4 st = make_float4(acc[ot][0] + s[0] + bz, acc[ot][1] + s[1] + bz,
                              acc[ot][2] + s[2] + bz, acc[ot][3] + s[3] + bz);
      *reinterpret_cast<float4*>(&out[(((size_t)bb * 64 + o) << 14) + hwbase]) = st;
    }
  }
}

extern "C" void kernel_launch(void* const* d_in, const int* in_sizes, int n_in,
                              void* d_out, int out_size, void* d_ws, size_t ws_size,
                              hipStream_t stream) {
  const float* x     = (const float*)d_in[0];
  const float* w_off = (const float*)d_in[1];
  const float* b_off = (const float*)d_in[2];
  const float* w     = (const float*)d_in[3];
  const float* bias  = (const float*)d_in[4];
  float* out = (float*)d_out;
  char* ws   = (char*)d_ws;

  // ws layout (BYTES):
  //   wfrag [0,       73,728)      36,864 bf16 (main-GEMM B, frag-ordered)
  //   wb    [73,728,  110,592)     18,432 bf16 (offsets-conv B frags)
  //   xt    [110,592, 8,763,392)   4*130*130*64 bf16 (padded, zero border)
  unsigned short* wfrag = (unsigned short*)(ws);
  unsigned short* wb    = (unsigned short*)(ws + 73728);
  unsigned short* xt    = (unsigned short*)(ws + 110592);

  hipLaunchKernelGGL(k_tr,   dim3(512),  dim3(256), 0, stream,
                     x, (unsigned int*)xt, w, w_off, wfrag, wb);
  hipLaunchKernelGGL(k_fuse, dim3(1024), dim3(512), 0, stream,
                     xt, wb, wfrag, b_off, bias, out);
}

// Round 16
// 40.446 us; speedup vs baseline: 1.4518x; 1.1745x over previous
//
#include <hip/hip_runtime.h>
#include <hip/hip_bf16.h>

#define HW 128
#define PW 130   // padded width/height

typedef float f32x4 __attribute__((ext_vector_type(4)));
typedef short bf16x8 __attribute__((ext_vector_type(8)));

__device__ __forceinline__ unsigned short f2bf(float v) {
  __hip_bfloat16 h = __float2bfloat16(v);
  return *reinterpret_cast<unsigned short*>(&h);
}

__device__ __forceinline__ void bf8_to_f32(const int4& r, float* f) {
  const unsigned int* u = reinterpret_cast<const unsigned int*>(&r);
#pragma unroll
  for (int k = 0; k < 4; ++k) {
    f[2 * k]     = __uint_as_float(u[k] << 16);
    f[2 * k + 1] = __uint_as_float(u[k] & 0xffff0000u);
  }
}

__device__ __forceinline__ void gld_lds16(const void* g, void* l) {
  __builtin_amdgcn_global_load_lds(
      (const __attribute__((address_space(1))) void*)g,
      (__attribute__((address_space(3))) void*)l, 16, 0, 0);
}

// ---------------- k_tr: prep + border-zero + NCHW->padded-NHWC transpose (r11-verified) ----
// wfrag: frag f = t*8 + ot*2 + kk; elem i = f*512 + lane*8 + j
//   wfrag[i] = bf16(w[o=ot*16+(lane&15)][c=(kk*4+(lane>>4))*8+j][t])
// wb: offsets-conv B frags (r8-verified layout).
__global__ __launch_bounds__(256) void k_tr(const float* __restrict__ x,
                                            unsigned int* __restrict__ xt_u32,
                                            const float* __restrict__ w,
                                            const float* __restrict__ w_off,
                                            unsigned short* __restrict__ wfrag,
                                            unsigned short* __restrict__ wb) {
  __shared__ float tile[64 * 129];
  int blk = blockIdx.x;                   // b*128 + h
  int tid = threadIdx.x;
  int gi = blk * 256 + tid;

  if (blk < 144) {
    if (gi < 36864) {
      int j = gi & 7, lane = (gi >> 3) & 63, f = gi >> 9;
      int kk = f & 1, ot = (f >> 1) & 3, t = f >> 3;
      int o = ot * 16 + (lane & 15);
      int c = (kk * 4 + (lane >> 4)) * 8 + j;
      wfrag[gi] = f2bf(w[o * 576 + c * 9 + t]);
    }
    if (gi < 18432) {
      int j = gi & 7, lane = (gi >> 3) & 63, f = gi >> 9;
      int n = f & 1, kk = (f >> 1) & 1, t = f >> 2;
      int o = n * 16 + (lane & 15);
      int c = kk * 32 + (lane >> 4) * 8 + j;
      float v = (o < 18) ? w_off[o * 576 + c * 9 + t] : 0.0f;
      wb[gi] = f2bf(v);
    }
  }
  if (gi < 16512) {
    int c4 = gi & 7, ci = gi >> 3;
    int b = ci / 516, cell = ci - b * 516;
    int row, col;
    if (cell < 130)      { row = 0;   col = cell; }
    else if (cell < 260) { row = 129; col = cell - 130; }
    else { int k = cell - 260; row = 1 + (k >> 1); col = (k & 1) ? 129 : 0; }
    reinterpret_cast<int4*>(xt_u32 + ((size_t)(b * PW + row) * PW + col) * 32)[c4] =
        make_int4(0, 0, 0, 0);
  }

  int h = blk & 127, b = blk >> 7;
  int w0 = tid & 127, ch = tid >> 7;
  const float* xb = x + ((size_t)b * 64 * HW + h) * HW;
#pragma unroll
  for (int k = 0; k < 32; ++k) {
    int c = ch * 32 + k;
    tile[c * 129 + (w0 ^ (c & 1))] = xb[c * (HW * HW) + w0];
  }
  __syncthreads();
  int c2 = tid & 31, wg = tid >> 5;
#pragma unroll
  for (int k = 0; k < 16; ++k) {
    int ww = wg * 16 + k;
    float lo = tile[(2 * c2) * 129 + ww];
    float hi = tile[(2 * c2 + 1) * 129 + (ww ^ 1)];
    xt_u32[((size_t)(b * PW + h + 1) * PW + (ww + 1)) * 32 + c2] =
        (unsigned int)f2bf(lo) | ((unsigned int)f2bf(hi) << 16);
  }
}

// ---------------- k_fuse: r11 structure + one-time geometry table ----------------
// LDS 30208 timeline:
//   phase 0:   slab [0,25344)
//   loff:      [0,4608)          (after barrier; slab dead)
//   geometry:  geo_off [16384,25600) int4/task, geo_yx [25600,30208) float2/task
//   main loop: ldsA dbuf [0,16384) (loff dead); geo regions live read-only
// 30208 B -> 5 blocks/CU (= r11's occupancy).
__global__ __launch_bounds__(256) void k_fuse(const unsigned short* __restrict__ xt,
                                              const unsigned short* __restrict__ wb,
                                              const unsigned short* __restrict__ wfrag,
                                              const float* __restrict__ b_off,
                                              const float* __restrict__ bias,
                                              float* __restrict__ out) {
  __shared__ __align__(16) char u_lds[30208];
  char* slab_b = u_lds;
  unsigned short* slab_us = (unsigned short*)u_lds;
  float* loff = (float*)u_lds;                       // [0,4608) after slab death
  int4*  geo_off = (int4*)(u_lds + 16384);           // [t*64+p]
  float2* geo_yx = (float2*)(u_lds + 25600);         // [t*64+p]

  int bid = blockIdx.x;
  bid = (bid & 7) * 128 + (bid >> 3);     // XCD swizzle (1024 % 8 == 0)
  int pix0 = bid * 64;
  int h = (pix0 >> 7) & 127, b = pix0 >> 14, wbase = pix0 & 127;

  int tid = threadIdx.x;
  int wid = tid >> 6, lane = tid & 63;
  int l15 = lane & 15, l4 = lane >> 4;
  int wm = wid >> 1, wn = wid & 1;
  int g = tid & 7, p2 = tid >> 3;

  const unsigned short* xb = xt + (size_t)b * (PW * PW * 64);
  const unsigned short* xtb = xb + g * 8;

  // ======== phase 0: offsets conv (r11-verified) ========
  for (int i = wid; i < 25; i += 4) {
    int e = i * 512 + lane * 8;
    if (e < 12672) {
      int S = e >> 6, c8 = (e >> 3) & 7;
      int r = S / 66, u = S - r * 66;
      gld_lds16(xb + ((size_t)((h + r) * PW + wbase + u)) * 64 + ((c8 ^ (S & 7)) << 3),
                &slab_us[i * 512]);
    }
  }

  const int4* wb4 = reinterpret_cast<const int4*>(wb);
  int4 bc[4], bn[4];
#pragma unroll
  for (int q = 0; q < 4; ++q) bc[q] = wb4[q * 64 + lane];
  asm volatile("s_waitcnt vmcnt(0)" ::: "memory");
  __builtin_amdgcn_s_barrier();

  f32x4 acc0 = {0.f, 0.f, 0.f, 0.f}, acc1 = {0.f, 0.f, 0.f, 0.f};
#pragma unroll 1
  for (int t = 0; t < 9; ++t) {
    if (t < 8) {
#pragma unroll
      for (int q = 0; q < 4; ++q) bn[q] = wb4[((t + 1) * 4 + q) * 64 + lane];
    }
    int ti = t / 3, tj = t - ti * 3;
    int S = ti * 66 + (wid * 16 + l15) + tj;
#pragma unroll
    for (int kk = 0; kk < 2; ++kk) {
      int phys = (kk * 4 + l4) ^ (S & 7);
      bf16x8 a = *reinterpret_cast<const bf16x8*>(slab_b + S * 128 + phys * 16);
      acc0 = __builtin_amdgcn_mfma_f32_16x16x32_bf16(a, *(const bf16x8*)&bc[kk * 2 + 0], acc0, 0, 0, 0);
      acc1 = __builtin_amdgcn_mfma_f32_16x16x32_bf16(a, *(const bf16x8*)&bc[kk * 2 + 1], acc1, 0, 0, 0);
    }
#pragma unroll
    for (int q = 0; q < 4; ++q) bc[q] = bn[q];
  }
  __syncthreads();   // all slab reads complete (loff overlays slab head)
  {
    float bo0 = b_off[l15];
    int pl = wid * 16 + l4 * 4;
#pragma unroll
    for (int reg = 0; reg < 4; ++reg)
      loff[(pl + reg) * 18 + l15] = acc0[reg] + bo0;
    if (l15 < 2) {
      float bo1 = b_off[16 + l15];
#pragma unroll
      for (int reg = 0; reg < 4; ++reg)
        loff[(pl + reg) * 18 + 16 + l15] = acc1[reg] + bo1;
    }
  }
  __syncthreads();   // loff visible

  // ======== geometry phase: one-time, 576 tasks (tap t, pixel p) ========
  for (int i = tid; i < 576; i += 256) {
    int p = i & 63, t = i >> 6;
    int ti = t / 3, tj = t - ti * 3;
    float2 d = *reinterpret_cast<const float2*>(&loff[p * 18 + 2 * t]);
    float py = (float)(h + ti - 1) + d.x;
    float px = (float)(wbase + p + tj - 1) + d.y;
    float y0f = floorf(py), x0f = floorf(px);
    float wy = py - y0f, wxf = px - x0f;
    int y0 = (int)y0f, x0 = (int)x0f;
    int y1 = y0 + 1, x1 = x0 + 1;
    int v00 = (((unsigned)y0 < HW) && ((unsigned)x0 < HW)) ? 1 : 0;
    int v01 = (((unsigned)y0 < HW) && ((unsigned)x1 < HW)) ? 1 : 0;
    int v10 = (((unsigned)y1 < HW) && ((unsigned)x0 < HW)) ? 1 : 0;
    int v11 = (((unsigned)y1 < HW) && ((unsigned)x1 < HW)) ? 1 : 0;
    int y0c = min(max(y0, 0), HW - 1) + 1, y1c = min(max(y1, 0), HW - 1) + 1;
    int x0c = min(max(x0, 0), HW - 1) + 1, x1c = min(max(x1, 0), HW - 1) + 1;
    int4 o4;
    o4.x = (y0c * PW + x0c) * 64 | (v00 << 31);
    o4.y = (y0c * PW + x1c) * 64 | (v01 << 31);
    o4.z = (y1c * PW + x0c) * 64 | (v10 << 31);
    o4.w = (y1c * PW + x1c) * 64 | (v11 << 31);
    geo_off[t * 64 + p] = o4;
    geo_yx[t * 64 + p] = make_float2(wy, wxf);
  }
  __syncthreads();   // geo ready; loff dead (ldsA may overlay)

  // ======== main loop (r11 structure; geometry from table) ========
  auto ldsAp = [&](int s) { return (unsigned short*)(u_lds + s * 8192); };

  int4 r[2][4];
  float fw[2][4];

  auto gather = [&](int t) {
#pragma unroll
    for (int k = 0; k < 2; ++k) {
      int pp = p2 + 32 * k;
      int4 o4 = geo_off[t * 64 + pp];          // broadcast across the 8 g-lanes
      float2 yx = geo_yx[t * 64 + pp];
      float wy = yx.x, wxf = yx.y;
      fw[k][0] = (o4.x < 0) ? (1.f - wy) * (1.f - wxf) : 0.f;
      fw[k][1] = (o4.y < 0) ? (1.f - wy) * wxf : 0.f;
      fw[k][2] = (o4.z < 0) ? wy * (1.f - wxf) : 0.f;
      fw[k][3] = (o4.w < 0) ? wy * wxf : 0.f;
      r[k][0] = *reinterpret_cast<const int4*>(xtb + (o4.x & 0x7FFFFFFF));
      r[k][1] = *reinterpret_cast<const int4*>(xtb + (o4.y & 0x7FFFFFFF));
      r[k][2] = *reinterpret_cast<const int4*>(xtb + (o4.z & 0x7FFFFFFF));
      r[k][3] = *reinterpret_cast<const int4*>(xtb + (o4.w & 0x7FFFFFFF));
    }
  };

  auto lerp_write = [&](int bsel) {
#pragma unroll
    for (int k = 0; k < 2; ++k) {
      int pp = p2 + 32 * k;
      float v00[8], v01[8], v10[8], v11[8];
      bf8_to_f32(r[k][0], v00); bf8_to_f32(r[k][1], v01);
      bf8_to_f32(r[k][2], v10); bf8_to_f32(r[k][3], v11);
      unsigned int pk[4];
#pragma unroll
      for (int j = 0; j < 4; ++j) {
        float slo = fmaf(v11[2 * j], fw[k][3],
                    fmaf(v10[2 * j], fw[k][2],
                    fmaf(v01[2 * j], fw[k][1], v00[2 * j] * fw[k][0])));
        float shi = fmaf(v11[2 * j + 1], fw[k][3],
                    fmaf(v10[2 * j + 1], fw[k][2],
                    fmaf(v01[2 * j + 1], fw[k][1], v00[2 * j + 1] * fw[k][0])));
        pk[j] = (unsigned int)f2bf(slo) | ((unsigned int)f2bf(shi) << 16);
      }
      *reinterpret_cast<int4*>(&ldsAp(bsel)[pp * 64 + ((g ^ (pp & 7)) << 3)]) =
          *reinterpret_cast<int4*>(pk);
    }
  };

  // main-GEMM B frags (r11-verified): Bc[fn*2+kk], frag = t*8 + (wn*2+fn)*2 + kk
  const int4* wf4 = reinterpret_cast<const int4*>(wfrag);
  int4 Bc[4], Bn[4];
#pragma unroll
  for (int q = 0; q < 4; ++q) {
    int fn = q >> 1, kk = q & 1;
    Bc[q] = wf4[((wn * 2 + fn) * 2 + kk) * 64 + lane];
  }

  f32x4 acc00 = {0.f, 0.f, 0.f, 0.f}, acc01 = {0.f, 0.f, 0.f, 0.f};
  f32x4 acc10 = {0.f, 0.f, 0.f, 0.f}, acc11 = {0.f, 0.f, 0.f, 0.f};

  gather(0);
  lerp_write(0);
  __syncthreads();                 // A0 ready

#pragma unroll 1
  for (int t = 0; t < 9; ++t) {
    int cur = t & 1;
    if (t < 8) {
#pragma unroll
      for (int q = 0; q < 4; ++q) {
        int fn = q >> 1, kk = q & 1;
        Bn[q] = wf4[(((t + 1) * 4 + wn * 2 + fn) * 2 + kk) * 64 + lane];
      }
      gather(t + 1);               // VMEM loads in flight under MFMA
    }
    const char* Ab = (const char*)ldsAp(cur);
#pragma unroll
    for (int kk = 0; kk < 2; ++kk) {
      int sw = (((kk * 4 + l4) ^ (l15 & 7)) << 4) + l15 * 128;
      bf16x8 a0 = *(const bf16x8*)(Ab + (wm * 32 + 0)  * 128 + sw);
      bf16x8 a1 = *(const bf16x8*)(Ab + (wm * 32 + 16) * 128 + sw);
      acc00 = __builtin_amdgcn_mfma_f32_16x16x32_bf16(a0, *(const bf16x8*)&Bc[0 * 2 + kk], acc00, 0, 0, 0);
      acc01 = __builtin_amdgcn_mfma_f32_16x16x32_bf16(a0, *(const bf16x8*)&Bc[1 * 2 + kk], acc01, 0, 0, 0);
      acc10 = __builtin_amdgcn_mfma_f32_16x16x32_bf16(a1, *(const bf16x8*)&Bc[0 * 2 + kk], acc10, 0, 0, 0);
      acc11 = __builtin_amdgcn_mfma_f32_16x16x32_bf16(a1, *(const bf16x8*)&Bc[1 * 2 + kk], acc11, 0, 0, 0);
    }
    if (t < 8) lerp_write(cur ^ 1);  // waits gather vmcnt here
#pragma unroll
    for (int q = 0; q < 4; ++q) Bc[q] = Bn[q];
    __syncthreads();
  }

  // epilogue (r11-verified)
  int m0 = wm * 32 + (l4 << 2);
#pragma unroll
  for (int fm = 0; fm < 2; ++fm) {
#pragma unroll
    for (int fn = 0; fn < 2; ++fn) {
      f32x4 a = (fm == 0) ? ((fn == 0) ? acc00 : acc01) : ((fn == 0) ? acc10 : acc11);
      int o = wn * 32 + fn * 16 + l15;
      int pix = pix0 + m0 + fm * 16;
      int bb = pix >> 14, hw = pix & 16383;
      float bz = bias[o];
      float4 st = make_float4(a[0] + bz, a[1] + bz, a[2] + bz, a[3] + bz);
      *reinterpret_cast<float4*>(&out[(((size_t)bb * 64 + o) << 14) + hw]) = st;
    }
  }
}

extern "C" void kernel_launch(void* const* d_in, const int* in_sizes, int n_in,
                              void* d_out, int out_size, void* d_ws, size_t ws_size,
                              hipStream_t stream) {
  const float* x     = (const float*)d_in[0];
  const float* w_off = (const float*)d_in[1];
  const float* b_off = (const float*)d_in[2];
  const float* w     = (const float*)d_in[3];
  const float* bias  = (const float*)d_in[4];
  float* out = (float*)d_out;
  char* ws   = (char*)d_ws;

  // ws layout (BYTES):
  //   wfrag [0,       73,728)      36,864 bf16 (main-GEMM B, frag-ordered)
  //   wb    [73,728,  110,592)     18,432 bf16 (offsets-conv B frags)
  //   xt    [110,592, 8,763,392)   4*130*130*64 bf16 (padded, zero border)
  unsigned short* wfrag = (unsigned short*)(ws);
  unsigned short* wb    = (unsigned short*)(ws + 73728);
  unsigned short* xt    = (unsigned short*)(ws + 110592);

  hipLaunchKernelGGL(k_tr,   dim3(512),  dim3(256), 0, stream,
                     x, (unsigned int*)xt, w, w_off, wfrag, wb);
  hipLaunchKernelGGL(k_fuse, dim3(1024), dim3(256), 0, stream,
                     xt, wb, wfrag, b_off, bias, out);
}